// Round 1
// baseline (265.512 us; speedup 1.0000x reference)
//
#include <hip/hip_runtime.h>
#include <cstdint>
#include <cstddef>

#define NROWS   32768
#define DIM     1024
#define NH      4
#define HD      256
#define NK      64
#define RPB     16           // rows per block = one MFMA M-tile
#define NBLK    (NROWS / RPB)   // 2048
#define THREADS 512          // 8 waves: 2 rows/wave (A,C), head-pair split (B)

typedef __attribute__((ext_vector_type(8))) short short8;   // 8 bf16 (4 VGPRs)
typedef __attribute__((ext_vector_type(4))) float float4a;  // MFMA acc

__device__ __forceinline__ unsigned short f2bf(float f) {
  unsigned int u = __float_as_uint(f);
  u += 0x7fffu + ((u >> 16) & 1u);   // RNE (no NaN inputs here)
  return (unsigned short)(u >> 16);
}
__device__ __forceinline__ float bflo(unsigned int u) {
  return __uint_as_float(u << 16);
}
__device__ __forceinline__ float bfhi(unsigned int u) {
  return __uint_as_float(u & 0xffff0000u);
}

// ---------------------------------------------------------------------------
// Pre-kernel: emb fp32 [4][64][256] -> bf16 B-fragment-linear layout in ws.
// granule g = ((h*4 + t)*8 + s)*64 + lane holds 8 bf16:
//   emb[h][t*16 + (lane&15)][s*32 + (lane>>4)*8 + 0..7]
// ---------------------------------------------------------------------------
__global__ __launch_bounds__(256) void vq_pre(const float* __restrict__ emb,
                                              unsigned short* __restrict__ ws_emb) {
  const int gid  = blockIdx.x * 256 + threadIdx.x;   // 0..8191
  const int lane = gid & 63;
  const int w    = gid >> 6;                          // (h*4 + t)*8 + s
  const int s = w & 7, ht = w >> 3, t = ht & 3, h = ht >> 2;
  const int code = t * 16 + (lane & 15);
  const int d0   = s * 32 + (lane >> 4) * 8;
  const float* p = emb + ((size_t)(h * NK + code)) * HD + d0;
  unsigned int w0 = f2bf(p[0]) | ((unsigned int)f2bf(p[1]) << 16);
  unsigned int w1 = f2bf(p[2]) | ((unsigned int)f2bf(p[3]) << 16);
  unsigned int w2 = f2bf(p[4]) | ((unsigned int)f2bf(p[5]) << 16);
  unsigned int w3 = f2bf(p[6]) | ((unsigned int)f2bf(p[7]) << 16);
  uint4 pk = make_uint4(w0, w1, w2, w3);
  *(uint4*)(ws_emb + (size_t)(w * 64 + lane) * 8) = pk;
}

// ---------------------------------------------------------------------------
// Main kernel, 512 threads (8 waves), 16 rows/block.
// Phase A: wave handles 2 rows; both rows prefetched, reductions interleaved.
// Phase B: wave = (head, code-tile-pair): 16 MFMAs; candidates to LDS.
// Combine: tid<64 merges the 2 candidates per (row,head).
// Phase C: gather-write q (2 rows/wave); loss wave 0; present-mask wave 1.
// ---------------------------------------------------------------------------
__global__ __launch_bounds__(THREADS, 8) void vq_main(
    const float* __restrict__ in, const float* __restrict__ lnw,
    const float* __restrict__ lnb, const float* __restrict__ emb,
    const unsigned short* __restrict__ ws_emb,
    float* __restrict__ out, float* __restrict__ ws)
{
  // x tile, bf16, fragment-swizzled: granule ((h*8+s)*4+q)*16 + (m^(q<<2)^s)
  __shared__ __align__(16) unsigned short xs[NH * 8 * 4 * 16 * 8]; // 32 KB
  __shared__ __align__(16) unsigned short wsh[DIM];  // ln weight, bf16 (2 KB)
  __shared__ __align__(16) unsigned short bsh[DIM];  // ln bias,   bf16 (2 KB)
  __shared__ float inv_s[RPB];
  __shared__ float base_s[RPB];                  // 4 + ssx*inv^2
  __shared__ __align__(16) int bidx_s[RPB][NH];
  __shared__ float bval_s[RPB][NH];
  __shared__ int flags_s[NH][NK];                // per-head present flags
  __shared__ float cva[RPB][NH][2];              // per (row,head) candidates
  __shared__ int   cia[RPB][NH][2];

  float* ws_loss = ws;                                             // [NBLK]
  unsigned long long* ws_mask = (unsigned long long*)(ws + NBLK);  // [NBLK]

  const int tid  = threadIdx.x;
  const int wave = tid >> 6;      // 0..7
  const int lane = tid & 63;
  const int row0 = blockIdx.x * RPB;

  // ---- weight loads first (oldest vmem ops -> their waitcnt leaves the
  //      input prefetch in flight), then input prefetch, then staging ----
  float4 w4, b4;
  if (tid < 256) {
    w4 = *(const float4*)(lnw + tid * 4);
    b4 = *(const float4*)(lnb + tid * 4);
  }

  const int m0 = wave * 2;        // two rows of this wave
  float4 v[2][4];
  #pragma unroll
  for (int rr = 0; rr < 2; ++rr) {
    const float* rp = in + (size_t)(row0 + m0 + rr) * DIM;
    #pragma unroll
    for (int c = 0; c < 4; ++c) v[rr][c] = *(const float4*)(rp + c * 256 + lane * 4);
  }

  if (tid < 256) {
    flags_s[tid >> 6][tid & 63] = 0;   // 256 ints
    uint2 wp, bp;
    wp.x = f2bf(w4.x) | ((unsigned int)f2bf(w4.y) << 16);
    wp.y = f2bf(w4.z) | ((unsigned int)f2bf(w4.w) << 16);
    bp.x = f2bf(b4.x) | ((unsigned int)f2bf(b4.y) << 16);
    bp.y = f2bf(b4.z) | ((unsigned int)f2bf(b4.w) << 16);
    *(uint2*)&wsh[tid * 4] = wp;
    *(uint2*)&bsh[tid * 4] = bp;
  }
  __syncthreads();

  // ---------------- Phase A: LN + soft-clip, 2 rows interleaved -------------
  const int sA = lane >> 3;          // k-step of this lane's dims
  const int qA = (lane >> 1) & 3;    // k-octet quad
  const int hfA = lane & 1;          // low/high half of octet
  const int msw0 = m0 ^ (qA << 2) ^ sA;   // msw1 = msw0 ^ 1

  float s1a = 0.f, s2a = 0.f, s1b = 0.f, s2b = 0.f;
  #pragma unroll
  for (int c = 0; c < 4; ++c) {
    s1a += (v[0][c].x + v[0][c].y) + (v[0][c].z + v[0][c].w);
    s2a = fmaf(v[0][c].x, v[0][c].x, s2a); s2a = fmaf(v[0][c].y, v[0][c].y, s2a);
    s2a = fmaf(v[0][c].z, v[0][c].z, s2a); s2a = fmaf(v[0][c].w, v[0][c].w, s2a);
    s1b += (v[1][c].x + v[1][c].y) + (v[1][c].z + v[1][c].w);
    s2b = fmaf(v[1][c].x, v[1][c].x, s2b); s2b = fmaf(v[1][c].y, v[1][c].y, s2b);
    s2b = fmaf(v[1][c].z, v[1][c].z, s2b); s2b = fmaf(v[1][c].w, v[1][c].w, s2b);
  }
  #pragma unroll
  for (int d = 1; d < 64; d <<= 1) {      // 4 independent chains
    s1a += __shfl_xor(s1a, d, 64);
    s2a += __shfl_xor(s2a, d, 64);
    s1b += __shfl_xor(s1b, d, 64);
    s2b += __shfl_xor(s2b, d, 64);
  }
  const float mu0   = s1a * (1.0f / 1024.0f);
  const float var0  = fmaf(-mu0, mu0, s2a * (1.0f / 1024.0f));
  const float rstd0 = rsqrtf(var0 + 1e-5f);
  const float mu1   = s1b * (1.0f / 1024.0f);
  const float var1  = fmaf(-mu1, mu1, s2b * (1.0f / 1024.0f));
  const float rstd1 = rsqrtf(var1 + 1e-5f);

  float ssa = 0.f, ssb = 0.f;
  #pragma unroll
  for (int c = 0; c < 4; ++c) {
    const uint2 wu = *(const uint2*)&wsh[c * 256 + lane * 4];
    const uint2 bu = *(const uint2*)&bsh[c * 256 + lane * 4];
    const float wf[4] = { bflo(wu.x), bfhi(wu.x), bflo(wu.y), bfhi(wu.y) };
    const float bf[4] = { bflo(bu.x), bfhi(bu.x), bflo(bu.y), bfhi(bu.y) };
    float* p0 = reinterpret_cast<float*>(&v[0][c]);
    float* p1 = reinterpret_cast<float*>(&v[1][c]);
    #pragma unroll
    for (int i = 0; i < 4; ++i) {
      float xh0 = (p0[i] - mu0) * rstd0;
      xh0 = fmaf(xh0, wf[i], bf[i]);
      // 5*tanh(xh/5) = 5*(1 - 2/(e^{0.4*xh}+1))
      const float e0 = __expf(0.4f * xh0);
      const float t0 = 1.f - 2.f * __builtin_amdgcn_rcpf(e0 + 1.f);
      const float x0 = 5.f * t0;
      ssa = fmaf(x0, x0, ssa);
      p0[i] = x0;

      float xh1 = (p1[i] - mu1) * rstd1;
      xh1 = fmaf(xh1, wf[i], bf[i]);
      const float e1 = __expf(0.4f * xh1);
      const float t1 = 1.f - 2.f * __builtin_amdgcn_rcpf(e1 + 1.f);
      const float x1 = 5.f * t1;
      ssb = fmaf(x1, x1, ssb);
      p1[i] = x1;
    }
    // store bf16 A-fragments (swizzled), both rows, chunk c
    const int gr = ((c * 8 + sA) * 4 + qA) * 16;
    uint2 pk0, pk1;
    pk0.x = f2bf(v[0][c].x) | ((unsigned int)f2bf(v[0][c].y) << 16);
    pk0.y = f2bf(v[0][c].z) | ((unsigned int)f2bf(v[0][c].w) << 16);
    pk1.x = f2bf(v[1][c].x) | ((unsigned int)f2bf(v[1][c].y) << 16);
    pk1.y = f2bf(v[1][c].z) | ((unsigned int)f2bf(v[1][c].w) << 16);
    *(uint2*)&xs[(gr + msw0) * 8 + hfA * 4] = pk0;
    *(uint2*)&xs[(gr + (msw0 ^ 1)) * 8 + hfA * 4] = pk1;
  }
  #pragma unroll
  for (int d = 1; d < 64; d <<= 1) {
    ssa += __shfl_xor(ssa, d, 64);
    ssb += __shfl_xor(ssb, d, 64);
  }
  if (lane == 0) {
    const float n0 = sqrtf(ssa);
    const float iv0 = 1.f / fmaxf(n0, 1e-5f);
    inv_s[m0]  = iv0;
    base_s[m0] = fmaf(ssa * iv0, iv0, 4.f);   // ||q||^2(=4) + ||xn||^2
    const float n1 = sqrtf(ssb);
    const float iv1 = 1.f / fmaxf(n1, 1e-5f);
    inv_s[m0 + 1]  = iv1;
    base_s[m0 + 1] = fmaf(ssb * iv1, iv1, 4.f);
  }
  __syncthreads();

  // ---------------- Phase B: MFMA distances + per-wave argmax ---------------
  {
    const int h = wave >> 1, tp = wave & 1;   // head, code-tile pair
    const int q = lane >> 4, mm = lane & 15;

    short8 afr[8];
    #pragma unroll
    for (int s = 0; s < 8; ++s) {
      const int gran = (h * 8 + s) * 64 + q * 16 + (mm ^ (q << 2) ^ s);
      afr[s] = *(const short8*)&xs[gran * 8];
    }

    const short8* eb = (const short8*)ws_emb + (size_t)h * 2048 + lane;
    float4a acc[2];
    #pragma unroll
    for (int tt = 0; tt < 2; ++tt) {
      #pragma unroll
      for (int r = 0; r < 4; ++r) acc[tt][r] = 0.f;
    }
    #pragma unroll
    for (int tt = 0; tt < 2; ++tt) {
      const int t = tp * 2 + tt;
      #pragma unroll
      for (int s = 0; s < 8; ++s) {
        const short8 bfr = eb[(t * 8 + s) * 64];
        acc[tt] = __builtin_amdgcn_mfma_f32_16x16x32_bf16(afr[s], bfr, acc[tt], 0, 0, 0);
      }
    }

    // acc[tt][r] = dist[row=q*4+r][code=(tp*2+tt)*16+mm]
    #pragma unroll
    for (int r = 0; r < 4; ++r) {
      float bv = acc[0][r];
      int   bi = (tp * 2) * 16 + mm;
      if (acc[1][r] > bv) { bv = acc[1][r]; bi = (tp * 2 + 1) * 16 + mm; }
      #pragma unroll
      for (int d = 1; d <= 8; d <<= 1) {
        const float ov = __shfl_xor(bv, d, 64);
        const int   oi = __shfl_xor(bi, d, 64);
        if (ov > bv || (ov == bv && oi < bi)) { bv = ov; bi = oi; }
      }
      if (mm == 0) {
        const int row = q * 4 + r;
        cva[row][h][tp] = bv;
        cia[row][h][tp] = bi;
      }
    }
  }
  __syncthreads();

  // ---------------- Combine the 2 candidates per (row, head) ----------------
  if (tid < 64) {
    const int row = tid >> 2, h = tid & 3;
    const float v0 = cva[row][h][0], v1 = cva[row][h][1];
    const int   i0 = cia[row][h][0], i1 = cia[row][h][1];
    // tie -> lower index; i0 < i1 always, so strict > for the high half
    int win = i0; float wv = v0;
    if (v1 > v0) { win = i1; wv = v1; }
    bidx_s[row][h] = win;
    bval_s[row][h] = wv;
    flags_s[h][win] = 1;       // benign write race (same value)
  }
  __syncthreads();

  // ---------------- Phase C: gather-write q; loss; present ------------------
  #pragma unroll
  for (int rr = 0; rr < 2; ++rr) {
    const int row = wave * 2 + rr;
    const int4 bi = *(const int4*)(&bidx_s[row][0]);
    const float4 q0 = *(const float4*)(emb + (size_t)(0 * NK + bi.x) * HD + lane * 4);
    const float4 q1 = *(const float4*)(emb + (size_t)(1 * NK + bi.y) * HD + lane * 4);
    const float4 q2 = *(const float4*)(emb + (size_t)(2 * NK + bi.z) * HD + lane * 4);
    const float4 q3 = *(const float4*)(emb + (size_t)(3 * NK + bi.w) * HD + lane * 4);
    float* op = out + (size_t)(row0 + row) * DIM + lane * 4;
    *(float4*)(op + 0)   = q0;
    *(float4*)(op + 256) = q1;
    *(float4*)(op + 512) = q2;
    *(float4*)(op + 768) = q3;
  }

  if (wave == 0) {
    float lsum = 0.f;
    if (lane < RPB) {
      const float ds = (bval_s[lane][0] + bval_s[lane][1]) +
                       (bval_s[lane][2] + bval_s[lane][3]);
      lsum = fmaf(-2.f * inv_s[lane], ds, base_s[lane]);
    }
    #pragma unroll
    for (int d = 1; d <= 8; d <<= 1) lsum += __shfl_xor(lsum, d, 64);
    if (lane == 0) ws_loss[blockIdx.x] = lsum;
  } else if (wave == 1) {
    const int f = flags_s[0][lane] | flags_s[1][lane] |
                  flags_s[2][lane] | flags_s[3][lane];
    const unsigned long long mk = __ballot(f != 0);
    if (lane == 0) ws_mask[blockIdx.x] = mk;
  }
}

__global__ __launch_bounds__(256) void vq_fin(const float* __restrict__ ws,
                                              float* __restrict__ out) {
  __shared__ float ls[4];
  __shared__ unsigned long long ms[4];
  const float* ws_loss = ws;
  const unsigned long long* ws_mask = (const unsigned long long*)(ws + NBLK);

  const int tid = threadIdx.x, wave = tid >> 6, lane = tid & 63;
  float l = 0.f;
  unsigned long long m = 0ull;
  for (int i = tid; i < NBLK; i += 256) { l += ws_loss[i]; m |= ws_mask[i]; }
  #pragma unroll
  for (int s = 1; s < 64; s <<= 1) {
    l += __shfl_xor(l, s, 64);
    m |= __shfl_xor(m, s, 64);
  }
  if (lane == 0) { ls[wave] = l; ms[wave] = m; }
  __syncthreads();
  if (tid == 0) {
    const float total = (ls[0] + ls[1]) + (ls[2] + ls[3]);
    const unsigned long long mm = ms[0] | ms[1] | ms[2] | ms[3];
    out[33554432] = 0.25f * total / 33554432.0f;
    out[33554433] = (float)__popcll(mm);
  }
}

extern "C" void kernel_launch(void* const* d_in, const int* in_sizes, int n_in,
                              void* d_out, int out_size, void* d_ws, size_t ws_size,
                              hipStream_t stream) {
  const float* in  = (const float*)d_in[0];
  const float* lnw = (const float*)d_in[1];
  const float* lnb = (const float*)d_in[2];
  const float* emb = (const float*)d_in[3];
  float* out = (float*)d_out;
  float* ws  = (float*)d_ws;

  // ws layout: [0,2048) loss floats | [2048, 2048+4096) mask u64s |
  //            byte offset 24576: emb bf16 fragments (131072 B)
  unsigned short* ws_emb = (unsigned short*)((char*)d_ws + 24576);

  vq_pre<<<32, 256, 0, stream>>>(emb, ws_emb);
  vq_main<<<NBLK, THREADS, 0, stream>>>(in, lnw, lnb, emb, ws_emb, out, ws);
  vq_fin<<<1, 256, 0, stream>>>(ws, out);
}

// Round 2
// 259.181 us; speedup vs baseline: 1.0244x; 1.0244x over previous
//
#include <hip/hip_runtime.h>
#include <cstdint>
#include <cstddef>

#define NROWS   32768
#define DIM     1024
#define NH      4
#define HD      256
#define NK      64
#define RPB     16           // rows per block = one MFMA M-tile
#define NBLK    (NROWS / RPB)   // 2048
#define THREADS 1024         // 16 waves: 1 row/wave (A,C), (head,tile) split (B)

typedef __attribute__((ext_vector_type(8))) short short8;   // 8 bf16 (4 VGPRs)
typedef __attribute__((ext_vector_type(4))) float float4a;  // MFMA acc

__device__ __forceinline__ unsigned short f2bf(float f) {
  unsigned int u = __float_as_uint(f);
  u += 0x7fffu + ((u >> 16) & 1u);   // RNE (no NaN inputs here)
  return (unsigned short)(u >> 16);
}
__device__ __forceinline__ float bflo(unsigned int u) {
  return __uint_as_float(u << 16);
}
__device__ __forceinline__ float bfhi(unsigned int u) {
  return __uint_as_float(u & 0xffff0000u);
}

// ---------------------------------------------------------------------------
// Pre-kernel: emb fp32 [4][64][256] -> bf16 B-fragment-linear layout in ws.
// granule g = ((h*4 + t)*8 + s)*64 + lane holds 8 bf16:
//   emb[h][t*16 + (lane&15)][s*32 + (lane>>4)*8 + 0..7]
// ---------------------------------------------------------------------------
__global__ __launch_bounds__(256) void vq_pre(const float* __restrict__ emb,
                                              unsigned short* __restrict__ ws_emb) {
  const int gid  = blockIdx.x * 256 + threadIdx.x;   // 0..8191
  const int lane = gid & 63;
  const int w    = gid >> 6;                          // (h*4 + t)*8 + s
  const int s = w & 7, ht = w >> 3, t = ht & 3, h = ht >> 2;
  const int code = t * 16 + (lane & 15);
  const int d0   = s * 32 + (lane >> 4) * 8;
  const float* p = emb + ((size_t)(h * NK + code)) * HD + d0;
  unsigned int w0 = f2bf(p[0]) | ((unsigned int)f2bf(p[1]) << 16);
  unsigned int w1 = f2bf(p[2]) | ((unsigned int)f2bf(p[3]) << 16);
  unsigned int w2 = f2bf(p[4]) | ((unsigned int)f2bf(p[5]) << 16);
  unsigned int w3 = f2bf(p[6]) | ((unsigned int)f2bf(p[7]) << 16);
  uint4 pk = make_uint4(w0, w1, w2, w3);
  *(uint4*)(ws_emb + (size_t)(w * 64 + lane) * 8) = pk;
}

// ---------------------------------------------------------------------------
// Main kernel, 1024 threads (16 waves), 16 rows/block.
// Phase A: wave handles 1 row (low VGPR pressure -> 8 waves/SIMD, no spill).
// Phase B: wave = (head, code-tile): 8 MFMAs; candidate per tile to LDS.
// Combine: tid<64 merges the 4 candidates per (row,head).
// Phase C: gather-write q (1 row/wave); loss wave 0; present-mask wave 1.
// ---------------------------------------------------------------------------
__global__ __launch_bounds__(THREADS, 8) void vq_main(
    const float* __restrict__ in, const float* __restrict__ lnw,
    const float* __restrict__ lnb, const float* __restrict__ emb,
    const unsigned short* __restrict__ ws_emb,
    float* __restrict__ out, float* __restrict__ ws)
{
  // x tile, bf16, fragment-swizzled: granule ((h*8+s)*4+q)*16 + (m^(q<<2)^s)
  __shared__ __align__(16) unsigned short xs[NH * 8 * 4 * 16 * 8]; // 32 KB
  __shared__ __align__(16) unsigned short wsh[DIM];  // ln weight, bf16 (2 KB)
  __shared__ __align__(16) unsigned short bsh[DIM];  // ln bias,   bf16 (2 KB)
  __shared__ float inv_s[RPB];
  __shared__ float base_s[RPB];                  // 4 + ssx*inv^2
  __shared__ __align__(16) int bidx_s[RPB][NH];
  __shared__ float bval_s[RPB][NH];
  __shared__ int flags_s[NH][NK];                // per-head present flags
  __shared__ float cva[RPB][NH][4];              // per (row,head) candidates
  __shared__ int   cia[RPB][NH][4];

  float* ws_loss = ws;                                             // [NBLK]
  unsigned long long* ws_mask = (unsigned long long*)(ws + NBLK);  // [NBLK]

  const int tid  = threadIdx.x;
  const int wave = tid >> 6;      // 0..15
  const int lane = tid & 63;
  const int row0 = blockIdx.x * RPB;

  // ---- weight loads first, then input prefetch, then staging ----
  float4 w4, b4;
  if (tid < 256) {
    w4 = *(const float4*)(lnw + tid * 4);
    b4 = *(const float4*)(lnb + tid * 4);
  }

  const int m = wave;             // this wave's row
  float4 v[4];
  {
    const float* rp = in + (size_t)(row0 + m) * DIM;
    #pragma unroll
    for (int c = 0; c < 4; ++c) v[c] = *(const float4*)(rp + c * 256 + lane * 4);
  }

  if (tid < 256) {
    flags_s[tid >> 6][tid & 63] = 0;   // 256 ints
    uint2 wp, bp;
    wp.x = f2bf(w4.x) | ((unsigned int)f2bf(w4.y) << 16);
    wp.y = f2bf(w4.z) | ((unsigned int)f2bf(w4.w) << 16);
    bp.x = f2bf(b4.x) | ((unsigned int)f2bf(b4.y) << 16);
    bp.y = f2bf(b4.z) | ((unsigned int)f2bf(b4.w) << 16);
    *(uint2*)&wsh[tid * 4] = wp;
    *(uint2*)&bsh[tid * 4] = bp;
  }
  __syncthreads();

  // ---------------- Phase A: LN + soft-clip, 1 row per wave -----------------
  const int sA = lane >> 3;          // k-step of this lane's dims
  const int qA = (lane >> 1) & 3;    // k-octet quad
  const int hfA = lane & 1;          // low/high half of octet
  const int msw = m ^ (qA << 2) ^ sA;

  float s1 = 0.f, s2 = 0.f;
  #pragma unroll
  for (int c = 0; c < 4; ++c) {
    s1 += (v[c].x + v[c].y) + (v[c].z + v[c].w);
    s2 = fmaf(v[c].x, v[c].x, s2); s2 = fmaf(v[c].y, v[c].y, s2);
    s2 = fmaf(v[c].z, v[c].z, s2); s2 = fmaf(v[c].w, v[c].w, s2);
  }
  #pragma unroll
  for (int d = 1; d < 64; d <<= 1) {
    s1 += __shfl_xor(s1, d, 64);
    s2 += __shfl_xor(s2, d, 64);
  }
  const float mu   = s1 * (1.0f / 1024.0f);
  const float var  = fmaf(-mu, mu, s2 * (1.0f / 1024.0f));
  const float rstd = rsqrtf(var + 1e-5f);

  float ss = 0.f;
  #pragma unroll
  for (int c = 0; c < 4; ++c) {
    const uint2 wu = *(const uint2*)&wsh[c * 256 + lane * 4];
    const uint2 bu = *(const uint2*)&bsh[c * 256 + lane * 4];
    const float wf[4] = { bflo(wu.x), bfhi(wu.x), bflo(wu.y), bfhi(wu.y) };
    const float bf[4] = { bflo(bu.x), bfhi(bu.x), bflo(bu.y), bfhi(bu.y) };
    float* pv = reinterpret_cast<float*>(&v[c]);
    #pragma unroll
    for (int i = 0; i < 4; ++i) {
      float xh = (pv[i] - mu) * rstd;
      xh = fmaf(xh, wf[i], bf[i]);
      // 5*tanh(xh/5) = 5*(1 - 2/(e^{0.4*xh}+1))
      const float e = __expf(0.4f * xh);
      const float t = 1.f - 2.f * __builtin_amdgcn_rcpf(e + 1.f);
      const float xx = 5.f * t;
      ss = fmaf(xx, xx, ss);
      pv[i] = xx;
    }
    // store bf16 A-fragments (swizzled), chunk c
    const int gran = ((c * 8 + sA) * 4 + qA) * 16 + msw;
    uint2 pk;
    pk.x = f2bf(v[c].x) | ((unsigned int)f2bf(v[c].y) << 16);
    pk.y = f2bf(v[c].z) | ((unsigned int)f2bf(v[c].w) << 16);
    *(uint2*)&xs[gran * 8 + hfA * 4] = pk;
  }
  #pragma unroll
  for (int d = 1; d < 64; d <<= 1) ss += __shfl_xor(ss, d, 64);

  if (lane == 0) {
    const float nrm = sqrtf(ss);
    const float iv  = 1.f / fmaxf(nrm, 1e-5f);
    inv_s[m]  = iv;
    base_s[m] = fmaf(ss * iv, iv, 4.f);   // ||q||^2(=4) + ||xn||^2
  }
  __syncthreads();

  // ---------------- Phase B: MFMA distances + per-wave argmax ---------------
  {
    const int h = wave >> 2, t = wave & 3;   // head, code tile
    const int q = lane >> 4, mm = lane & 15;

    short8 afr[8];
    #pragma unroll
    for (int s = 0; s < 8; ++s) {
      const int gran = (h * 8 + s) * 64 + q * 16 + (mm ^ (q << 2) ^ s);
      afr[s] = *(const short8*)&xs[gran * 8];
    }

    const short8* eb = (const short8*)ws_emb + (size_t)h * 2048 + lane;
    float4a acc;
    #pragma unroll
    for (int r = 0; r < 4; ++r) acc[r] = 0.f;
    #pragma unroll
    for (int s = 0; s < 8; ++s) {
      const short8 bfr = eb[(t * 8 + s) * 64];
      acc = __builtin_amdgcn_mfma_f32_16x16x32_bf16(afr[s], bfr, acc, 0, 0, 0);
    }

    // acc[r] = dist[row=q*4+r][code=t*16+mm]
    #pragma unroll
    for (int r = 0; r < 4; ++r) {
      float bv = acc[r];
      int   bi = t * 16 + mm;
      #pragma unroll
      for (int d = 1; d <= 8; d <<= 1) {
        const float ov = __shfl_xor(bv, d, 64);
        const int   oi = __shfl_xor(bi, d, 64);
        if (ov > bv || (ov == bv && oi < bi)) { bv = ov; bi = oi; }
      }
      if (mm == 0) {
        const int row = q * 4 + r;
        cva[row][h][t] = bv;
        cia[row][h][t] = bi;
      }
    }
  }
  __syncthreads();

  // ---------------- Combine the 4 candidates per (row, head) ----------------
  if (tid < 64) {
    const int row = tid >> 2, h = tid & 3;
    // candidates are in ascending-index order; strict > keeps lowest index
    float wv = cva[row][h][0];
    int   win = cia[row][h][0];
    #pragma unroll
    for (int t = 1; t < 4; ++t) {
      const float v1 = cva[row][h][t];
      const int   i1 = cia[row][h][t];
      if (v1 > wv) { wv = v1; win = i1; }
    }
    bidx_s[row][h] = win;
    bval_s[row][h] = wv;
    flags_s[h][win] = 1;       // benign write race (same value)
  }
  __syncthreads();

  // ---------------- Phase C: gather-write q; loss; present ------------------
  {
    const int row = wave;
    const int4 bi = *(const int4*)(&bidx_s[row][0]);
    const float4 q0 = *(const float4*)(emb + (size_t)(0 * NK + bi.x) * HD + lane * 4);
    const float4 q1 = *(const float4*)(emb + (size_t)(1 * NK + bi.y) * HD + lane * 4);
    const float4 q2 = *(const float4*)(emb + (size_t)(2 * NK + bi.z) * HD + lane * 4);
    const float4 q3 = *(const float4*)(emb + (size_t)(3 * NK + bi.w) * HD + lane * 4);
    float* op = out + (size_t)(row0 + row) * DIM + lane * 4;
    *(float4*)(op + 0)   = q0;
    *(float4*)(op + 256) = q1;
    *(float4*)(op + 512) = q2;
    *(float4*)(op + 768) = q3;
  }

  if (wave == 0) {
    float lsum = 0.f;
    if (lane < RPB) {
      const float ds = (bval_s[lane][0] + bval_s[lane][1]) +
                       (bval_s[lane][2] + bval_s[lane][3]);
      lsum = fmaf(-2.f * inv_s[lane], ds, base_s[lane]);
    }
    #pragma unroll
    for (int d = 1; d <= 8; d <<= 1) lsum += __shfl_xor(lsum, d, 64);
    if (lane == 0) ws_loss[blockIdx.x] = lsum;
  } else if (wave == 1) {
    const int f = flags_s[0][lane] | flags_s[1][lane] |
                  flags_s[2][lane] | flags_s[3][lane];
    const unsigned long long mk = __ballot(f != 0);
    if (lane == 0) ws_mask[blockIdx.x] = mk;
  }
}

__global__ __launch_bounds__(256) void vq_fin(const float* __restrict__ ws,
                                              float* __restrict__ out) {
  __shared__ float ls[4];
  __shared__ unsigned long long ms[4];
  const float* ws_loss = ws;
  const unsigned long long* ws_mask = (const unsigned long long*)(ws + NBLK);

  const int tid = threadIdx.x, wave = tid >> 6, lane = tid & 63;
  float l = 0.f;
  unsigned long long m = 0ull;
  for (int i = tid; i < NBLK; i += 256) { l += ws_loss[i]; m |= ws_mask[i]; }
  #pragma unroll
  for (int s = 1; s < 64; s <<= 1) {
    l += __shfl_xor(l, s, 64);
    m |= __shfl_xor(m, s, 64);
  }
  if (lane == 0) { ls[wave] = l; ms[wave] = m; }
  __syncthreads();
  if (tid == 0) {
    const float total = (ls[0] + ls[1]) + (ls[2] + ls[3]);
    const unsigned long long mm = ms[0] | ms[1] | ms[2] | ms[3];
    out[33554432] = 0.25f * total / 33554432.0f;
    out[33554433] = (float)__popcll(mm);
  }
}

extern "C" void kernel_launch(void* const* d_in, const int* in_sizes, int n_in,
                              void* d_out, int out_size, void* d_ws, size_t ws_size,
                              hipStream_t stream) {
  const float* in  = (const float*)d_in[0];
  const float* lnw = (const float*)d_in[1];
  const float* lnb = (const float*)d_in[2];
  const float* emb = (const float*)d_in[3];
  float* out = (float*)d_out;
  float* ws  = (float*)d_ws;

  // ws layout: [0,2048) loss floats | [2048, 2048+4096) mask u64s |
  //            byte offset 24576: emb bf16 fragments (131072 B)
  unsigned short* ws_emb = (unsigned short*)((char*)d_ws + 24576);

  vq_pre<<<32, 256, 0, stream>>>(emb, ws_emb);
  vq_main<<<NBLK, THREADS, 0, stream>>>(in, lnw, lnb, emb, ws_emb, out, ws);
  vq_fin<<<1, 256, 0, stream>>>(ws, out);
}